// Round 15
// baseline (69.004 us; speedup 1.0000x reference)
//
#include <hip/hip_runtime.h>
#include <cstdint>
#include <cstddef>

#define CCH   512
#define FSCOPE 27
#define HWSP  3136
#define NBATCH 16
#define NCOL  (NBATCH*HWSP)   // 50176

#define BM 128
#define BN 128
#define BK 64
#define NBT 6                 // band K-tiles: k in [m0-128, m0+255], 6*64=384

#define PI_F 3.14159265358979323846f

typedef __bf16 bf16x8 __attribute__((ext_vector_type(8)));
typedef float  f32x4  __attribute__((ext_vector_type(4)));

static __device__ __forceinline__ unsigned short f2bf(float f) {
  unsigned u = __builtin_bit_cast(unsigned, f);
  unsigned r = 0x7FFFu + ((u >> 16) & 1u);
  return (unsigned short)((u + r) >> 16);
}

// ---- kernel 1 (fused fk + inverse DFT, parallel over d):
__global__ __launch_bounds__(512)
void k_h2(const float* __restrict__ w, float* __restrict__ h) {
  __shared__ float red[8];
  const int d = blockIdx.x;
  const int m = threadIdx.x;

  float re = 1.0f, im = 0.0f;
  #pragma unroll
  for (int j = 0; j < FSCOPE; ++j) {
    int t = (m * (j - FSCOPE/2)) % CCH;
    if (t < 0) t += CCH;
    float ang = (2.0f * PI_F / CCH) * (float)t;
    float s, c;
    sincosf(ang, &s, &c);
    float wj = w[j];
    re -= wj * c;
    im += wj * s;
  }

  int t = (m * d) & (CCH - 1);
  float ang = (2.0f * PI_F / CCH) * (float)t;
  float s, c;
  sincosf(ang, &s, &c);
  float inv = 1.0f / (re * re + im * im);
  float term = (c * re + s * im) * inv;

  #pragma unroll
  for (int off = 32; off > 0; off >>= 1)
    term += __shfl_down(term, off, 64);

  const int lane = m & 63, wv = m >> 6;
  if (lane == 0) red[wv] = term;
  __syncthreads();
  if (m == 0) {
    float tot = 0.f;
    #pragma unroll
    for (int i = 0; i < 8; ++i) tot += red[i];
    h[d] = tot / (float)CCH;
  }
}

// ---- kernel 2: H[m][k] = bf16( h[(m-k) mod 512] ), row-major 512x512
__global__ void k_buildH(const float* __restrict__ h, unsigned short* __restrict__ Hm) {
  int m = blockIdx.x;
  for (int k = threadIdx.x; k < CCH; k += blockDim.x) {
    Hm[m*CCH + k] = f2bf(h[(m - k) & (CCH - 1)]);
  }
}

// ---- kernel 3: Y = H * X — r11 schedule + BAND TRUNCATION.
// h = (delta-k)^-1 has ||k||_1 ~ 0.443 -> |h[d]| mass beyond |d|>128 is
// <= sum_{n>=10} 0.443^n ~ 5e-4 (output err ~0.003 << 0.079 margin).
// Each m-tile therefore needs only k in [m0-128, m0+255]: 6 of 8 K-tiles.
// grid = 4 m-tiles * 392 col-tiles = 1568 blocks, 256 threads (4 waves)
// LDS 48KB: A0@0, A1@16K, B@32K -> 3 blocks/CU.
// Per iter: issue DMA-A(t+1)->A[nxt] + load bv(t+1); compute(t); sync1;
// writeB(t+1); sync2.
__global__ __launch_bounds__(256)
void k_gemm(const float* __restrict__ X, const unsigned short* __restrict__ Hm,
            float* __restrict__ Y) {
  __shared__ __align__(16) unsigned char lds[49152];

  const int tid  = threadIdx.x;
  const int lane = tid & 63;
  const int w    = tid >> 6;

  // XCD-aware swizzle (1568 = 8 * 196, exact)
  int bid = blockIdx.x;
  int cpx = gridDim.x >> 3;
  int swz = (bid & 7) * cpx + (bid >> 3);
  const int tm = swz & 3;
  const int tc = swz >> 2;

  const int m0 = tm * BM;
  const int j0 = tc * BN;

  // first band K-tile (global index): (m0 - 128)/64 mod 8
  const int kt0 = (tm * 2 + 6) & 7;

  unsigned char* Bl = lds + 32768;

  // B staging mapping: thread -> 4 cols (float4) x 8 k's
  const int fg = tid & 31;
  const int kg = tid >> 5;
  const int jb = j0 + fg*4;
  const int nb = jb / HWSP;      // float4 never crosses batch (3136 % 4 == 0)
  const int sb = jb - nb * HWSP;
  const float* Xb = X + (size_t)nb * (CCH*(size_t)HWSP) + sb;

  // B swizzle: g(col) = (col&7) ^ ((col>>3)&7); slot = kq ^ g(col).
  int wrOff[4];
  #pragma unroll
  for (int c = 0; c < 4; ++c) {
    int col = fg*4 + c;
    int g = (col & 7) ^ ((col >> 3) & 7);
    wrOff[c] = col*128 + (((kg ^ g) & 7) << 4);
  }

  const int wr = w >> 1, wc = w & 1;   // wave -> 64x64 quadrant
  int aBase[4], aSw[4], bBase[4], bSw[4];
  #pragma unroll
  for (int fm = 0; fm < 4; ++fm) {
    int m = wr*64 + fm*16 + (lane & 15);
    aBase[fm] = m*128;
    aSw[fm]   = (m & 7) << 4;
  }
  #pragma unroll
  for (int fn = 0; fn < 4; ++fn) {
    int col = wc*64 + fn*16 + (lane & 15);
    bBase[fn] = col*128;
    bSw[fn]   = ((col & 7) ^ ((col >> 3) & 7)) << 4;
  }

  // A DMA lane mapping: wave-uniform dst, pre-swizzled src
  const int aRow = lane >> 3;
  const int aChk = lane & 7;

  f32x4 acc[4][4];
  #pragma unroll
  for (int i = 0; i < 4; ++i)
    #pragma unroll
    for (int j = 0; j < 4; ++j)
      acc[i][j] = (f32x4){0.f, 0.f, 0.f, 0.f};

  float4 bv[8];

  // ---- prologue: DMA A(band tile 0) -> A0, load bv, publish B
  {
    const int kglob = kt0 * BK;
    #pragma unroll
    for (int i = 0; i < 4; ++i) {
      int m0w = w*32 + i*8;
      int m   = m0w + aRow;
      const unsigned short* src =
          Hm + (size_t)(m0 + m) * CCH + kglob + 8*(aChk ^ (m & 7));
      __builtin_amdgcn_global_load_lds(
          (const __attribute__((address_space(1))) void*)src,
          (__attribute__((address_space(3))) void*)(lds + m0w*128), 16, 0, 0);
    }
    #pragma unroll
    for (int kk = 0; kk < 8; ++kk)
      bv[kk] = *reinterpret_cast<const float4*>(Xb + (size_t)(kglob + kg*8 + kk) * HWSP);
  }
  __syncthreads();   // drains DMA(0) + bv(0)
  #pragma unroll
  for (int c = 0; c < 4; ++c) {
    union { __bf16 h[8]; int4 v; } u;
    #pragma unroll
    for (int kk = 0; kk < 8; ++kk) {
      float f = (c==0) ? bv[kk].x : (c==1) ? bv[kk].y : (c==2) ? bv[kk].z : bv[kk].w;
      u.h[kk] = (__bf16)f;
    }
    *reinterpret_cast<int4*>(Bl + wrOff[c]) = u.v;
  }
  __syncthreads();   // B(0) visible

  // ---- main loop over the 6 band K-tiles
  for (int kt = 0; kt < NBT; ++kt) {
    const int aoffC = (kt & 1) * 16384;
    const int aoffN = 16384 - aoffC;

    // issue next band tile's A-DMA and B-loads BEFORE compute
    if (kt + 1 < NBT) {
      const int kglob = ((kt0 + kt + 1) & 7) * BK;
      #pragma unroll
      for (int i = 0; i < 4; ++i) {
        int m0w = w*32 + i*8;
        int m   = m0w + aRow;
        const unsigned short* src =
            Hm + (size_t)(m0 + m) * CCH + kglob + 8*(aChk ^ (m & 7));
        __builtin_amdgcn_global_load_lds(
            (const __attribute__((address_space(1))) void*)src,
            (__attribute__((address_space(3))) void*)(lds + aoffN + m0w*128), 16, 0, 0);
      }
      const float* Xk = Xb + (size_t)(kglob + kg*8) * HWSP;
      #pragma unroll
      for (int kk = 0; kk < 8; ++kk)
        bv[kk] = *reinterpret_cast<const float4*>(Xk + (size_t)kk * HWSP);
    }

    // compute band tile kt from A[cur] and B
    #pragma unroll
    for (int ks = 0; ks < 2; ++ks) {
      const int kbyte = ks*64 + ((lane >> 4) << 4);
      bf16x8 af[4], bfr[4];
      #pragma unroll
      for (int fm = 0; fm < 4; ++fm)
        af[fm] = *reinterpret_cast<const bf16x8*>(lds + aoffC + aBase[fm] + (kbyte ^ aSw[fm]));
      #pragma unroll
      for (int fn = 0; fn < 4; ++fn)
        bfr[fn] = *reinterpret_cast<const bf16x8*>(Bl + bBase[fn] + (kbyte ^ bSw[fn]));
      #pragma unroll
      for (int fm = 0; fm < 4; ++fm)
        #pragma unroll
        for (int fn = 0; fn < 4; ++fn)
          acc[fm][fn] = __builtin_amdgcn_mfma_f32_16x16x32_bf16(
              af[fm], bfr[fn], acc[fm][fn], 0, 0, 0);
    }

    __syncthreads();   // sync1: B consumed by all; DMA(kt+1) drained

    if (kt + 1 < NBT) {
      #pragma unroll
      for (int c = 0; c < 4; ++c) {
        union { __bf16 h[8]; int4 v; } u;
        #pragma unroll
        for (int kk = 0; kk < 8; ++kk) {
          float f = (c==0) ? bv[kk].x : (c==1) ? bv[kk].y : (c==2) ? bv[kk].z : bv[kk].w;
          u.h[kk] = (__bf16)f;
        }
        *reinterpret_cast<int4*>(Bl + wrOff[c]) = u.v;
      }
      __syncthreads(); // sync2: B(kt+1) visible
    }
  }

  // epilogue: C/D layout col = lane&15, row = (lane>>4)*4 + r  (m89/m91)
  #pragma unroll
  for (int fn = 0; fn < 4; ++fn) {
    int colg = j0 + wc*64 + fn*16 + (lane & 15);
    int n = colg / HWSP;
    int s = colg - n * HWSP;
    float* Yb = Y + (size_t)n * (CCH*(size_t)HWSP) + s;
    #pragma unroll
    for (int fm = 0; fm < 4; ++fm) {
      int mrow = m0 + wr*64 + fm*16 + ((lane >> 4) << 2);
      #pragma unroll
      for (int r = 0; r < 4; ++r)
        Yb[(size_t)(mrow + r) * HWSP] = acc[fm][fn][r];
    }
  }
}

extern "C" void kernel_launch(void* const* d_in, const int* in_sizes, int n_in,
                              void* d_out, int out_size, void* d_ws, size_t ws_size,
                              hipStream_t stream) {
  const float* X = (const float*)d_in[0];   // [16,512,56,56] f32
  const float* w = (const float*)d_in[1];   // [27] f32
  float* Y = (float*)d_out;

  float* h           = (float*)d_ws;                                // 2 KB
  unsigned short* Hm = (unsigned short*)((char*)d_ws + 4096);       // 512 KB

  k_h2    <<<CCH, 512, 0, stream>>>(w, h);
  k_buildH<<<CCH, 256, 0, stream>>>(h, Hm);

  const int nblk = (CCH/BM) * (NCOL/BN);    // 4 * 392 = 1568
  k_gemm  <<<nblk, 256, 0, stream>>>(X, Hm, Y);
}

// Round 16
// 60.008 us; speedup vs baseline: 1.1499x; 1.1499x over previous
//
#include <hip/hip_runtime.h>
#include <cstdint>
#include <cstddef>

#define CCH   512
#define FSCOPE 27
#define HWSP  3136
#define NBATCH 16
#define NCOL  (NBATCH*HWSP)   // 50176

#define BM 128
#define BN 128
#define BK 64
#define NKT (CCH/BK)          // 8

#define PI_F 3.14159265358979323846f

typedef __bf16 bf16x8 __attribute__((ext_vector_type(8)));
typedef float  f32x4  __attribute__((ext_vector_type(4)));

static __device__ __forceinline__ unsigned short f2bf(float f) {
  unsigned u = __builtin_bit_cast(unsigned, f);
  unsigned r = 0x7FFFu + ((u >> 16) & 1u);
  return (unsigned short)((u + r) >> 16);
}

// ---- kernel 1 (fused fk + inverse DFT, parallel over d):
__global__ __launch_bounds__(512)
void k_h2(const float* __restrict__ w, float* __restrict__ h) {
  __shared__ float red[8];
  const int d = blockIdx.x;
  const int m = threadIdx.x;

  float re = 1.0f, im = 0.0f;
  #pragma unroll
  for (int j = 0; j < FSCOPE; ++j) {
    int t = (m * (j - FSCOPE/2)) % CCH;
    if (t < 0) t += CCH;
    float ang = (2.0f * PI_F / CCH) * (float)t;
    float s, c;
    sincosf(ang, &s, &c);
    float wj = w[j];
    re -= wj * c;
    im += wj * s;
  }

  int t = (m * d) & (CCH - 1);
  float ang = (2.0f * PI_F / CCH) * (float)t;
  float s, c;
  sincosf(ang, &s, &c);
  float inv = 1.0f / (re * re + im * im);
  float term = (c * re + s * im) * inv;

  #pragma unroll
  for (int off = 32; off > 0; off >>= 1)
    term += __shfl_down(term, off, 64);

  const int lane = m & 63, wv = m >> 6;
  if (lane == 0) red[wv] = term;
  __syncthreads();
  if (m == 0) {
    float tot = 0.f;
    #pragma unroll
    for (int i = 0; i < 8; ++i) tot += red[i];
    h[d] = tot / (float)CCH;
  }
}

// ---- kernel 2: H[m][k] = bf16( h[(m-k) mod 512] ), row-major 512x512
__global__ void k_buildH(const float* __restrict__ h, unsigned short* __restrict__ Hm) {
  int m = blockIdx.x;
  for (int k = threadIdx.x; k < CCH; k += blockDim.x) {
    Hm[m*CCH + k] = f2bf(h[(m - k) & (CCH - 1)]);
  }
}

// ---- kernel 3: Y = H * X — r11: A-dbuf + hoisted prefetch (best known).
// grid = 4 m-tiles * 392 col-tiles = 1568 blocks, 256 threads (4 waves)
// LDS 48KB: A0@0 (16K), A1@16K, B@32K (16K) -> 3 blocks/CU.
// Per iter: issue DMA-A(t+1)->A[nxt] + load bv(t+1); compute(t); sync1
// (drains DMA, ~overlapped); writeB(t+1); sync2.
__global__ __launch_bounds__(256)
void k_gemm(const float* __restrict__ X, const unsigned short* __restrict__ Hm,
            float* __restrict__ Y) {
  __shared__ __align__(16) unsigned char lds[49152];

  const int tid  = threadIdx.x;
  const int lane = tid & 63;
  const int w    = tid >> 6;

  // XCD-aware swizzle (1568 = 8 * 196, exact)
  int bid = blockIdx.x;
  int cpx = gridDim.x >> 3;
  int swz = (bid & 7) * cpx + (bid >> 3);
  const int tm = swz & 3;
  const int tc = swz >> 2;

  const int m0 = tm * BM;
  const int j0 = tc * BN;

  unsigned char* Bl = lds + 32768;

  // B staging mapping: thread -> 4 cols (float4) x 8 k's
  const int fg = tid & 31;
  const int kg = tid >> 5;
  const int jb = j0 + fg*4;
  const int nb = jb / HWSP;      // float4 never crosses batch (3136 % 4 == 0)
  const int sb = jb - nb * HWSP;
  const float* Xb = X + (size_t)nb * (CCH*(size_t)HWSP) + sb;

  // B swizzle: g(col) = (col&7) ^ ((col>>3)&7); slot = kq ^ g(col).
  int wrOff[4];
  #pragma unroll
  for (int c = 0; c < 4; ++c) {
    int col = fg*4 + c;
    int g = (col & 7) ^ ((col >> 3) & 7);
    wrOff[c] = col*128 + (((kg ^ g) & 7) << 4);
  }

  const int wr = w >> 1, wc = w & 1;   // wave -> 64x64 quadrant
  int aBase[4], aSw[4], bBase[4], bSw[4];
  #pragma unroll
  for (int fm = 0; fm < 4; ++fm) {
    int m = wr*64 + fm*16 + (lane & 15);
    aBase[fm] = m*128;
    aSw[fm]   = (m & 7) << 4;
  }
  #pragma unroll
  for (int fn = 0; fn < 4; ++fn) {
    int col = wc*64 + fn*16 + (lane & 15);
    bBase[fn] = col*128;
    bSw[fn]   = ((col & 7) ^ ((col >> 3) & 7)) << 4;
  }

  // A DMA lane mapping: wave-uniform dst, pre-swizzled src
  const int aRow = lane >> 3;
  const int aChk = lane & 7;

  f32x4 acc[4][4];
  #pragma unroll
  for (int i = 0; i < 4; ++i)
    #pragma unroll
    for (int j = 0; j < 4; ++j)
      acc[i][j] = (f32x4){0.f, 0.f, 0.f, 0.f};

  float4 bv[8];

  // ---- prologue: DMA A(0) -> A0, load bv(0), publish B(0)
  #pragma unroll
  for (int i = 0; i < 4; ++i) {
    int m0w = w*32 + i*8;
    int m   = m0w + aRow;
    const unsigned short* src =
        Hm + (size_t)(m0 + m) * CCH + 8*(aChk ^ (m & 7));
    __builtin_amdgcn_global_load_lds(
        (const __attribute__((address_space(1))) void*)src,
        (__attribute__((address_space(3))) void*)(lds + m0w*128), 16, 0, 0);
  }
  #pragma unroll
  for (int kk = 0; kk < 8; ++kk)
    bv[kk] = *reinterpret_cast<const float4*>(Xb + (size_t)(kg*8 + kk) * HWSP);
  __syncthreads();   // drains DMA(0) + bv(0)
  #pragma unroll
  for (int c = 0; c < 4; ++c) {
    union { __bf16 h[8]; int4 v; } u;
    #pragma unroll
    for (int kk = 0; kk < 8; ++kk) {
      float f = (c==0) ? bv[kk].x : (c==1) ? bv[kk].y : (c==2) ? bv[kk].z : bv[kk].w;
      u.h[kk] = (__bf16)f;
    }
    *reinterpret_cast<int4*>(Bl + wrOff[c]) = u.v;
  }
  __syncthreads();   // B(0) visible

  // ---- main loop
  for (int kt = 0; kt < NKT; ++kt) {
    const int aoffC = (kt & 1) * 16384;
    const int aoffN = 16384 - aoffC;

    // issue next tile's A-DMA and B-loads BEFORE compute (latency overlap)
    if (kt + 1 < NKT) {
      #pragma unroll
      for (int i = 0; i < 4; ++i) {
        int m0w = w*32 + i*8;
        int m   = m0w + aRow;
        const unsigned short* src =
            Hm + (size_t)(m0 + m) * CCH + (kt + 1)*BK + 8*(aChk ^ (m & 7));
        __builtin_amdgcn_global_load_lds(
            (const __attribute__((address_space(1))) void*)src,
            (__attribute__((address_space(3))) void*)(lds + aoffN + m0w*128), 16, 0, 0);
      }
      const float* Xk = Xb + (size_t)((kt + 1)*BK + kg*8) * HWSP;
      #pragma unroll
      for (int kk = 0; kk < 8; ++kk)
        bv[kk] = *reinterpret_cast<const float4*>(Xk + (size_t)kk * HWSP);
    }

    // compute tile kt from A[cur] and B
    #pragma unroll
    for (int ks = 0; ks < 2; ++ks) {
      const int kbyte = ks*64 + ((lane >> 4) << 4);
      bf16x8 af[4], bfr[4];
      #pragma unroll
      for (int fm = 0; fm < 4; ++fm)
        af[fm] = *reinterpret_cast<const bf16x8*>(lds + aoffC + aBase[fm] + (kbyte ^ aSw[fm]));
      #pragma unroll
      for (int fn = 0; fn < 4; ++fn)
        bfr[fn] = *reinterpret_cast<const bf16x8*>(Bl + bBase[fn] + (kbyte ^ bSw[fn]));
      #pragma unroll
      for (int fm = 0; fm < 4; ++fm)
        #pragma unroll
        for (int fn = 0; fn < 4; ++fn)
          acc[fm][fn] = __builtin_amdgcn_mfma_f32_16x16x32_bf16(
              af[fm], bfr[fn], acc[fm][fn], 0, 0, 0);
    }

    __syncthreads();   // sync1: all waves done with B(kt); DMA(kt+1) drained

    if (kt + 1 < NKT) {
      #pragma unroll
      for (int c = 0; c < 4; ++c) {
        union { __bf16 h[8]; int4 v; } u;
        #pragma unroll
        for (int kk = 0; kk < 8; ++kk) {
          float f = (c==0) ? bv[kk].x : (c==1) ? bv[kk].y : (c==2) ? bv[kk].z : bv[kk].w;
          u.h[kk] = (__bf16)f;
        }
        *reinterpret_cast<int4*>(Bl + wrOff[c]) = u.v;
      }
      __syncthreads(); // sync2: B(kt+1) visible
    }
  }

  // epilogue: C/D layout col = lane&15, row = (lane>>4)*4 + r  (m89/m91)
  #pragma unroll
  for (int fn = 0; fn < 4; ++fn) {
    int colg = j0 + wc*64 + fn*16 + (lane & 15);
    int n = colg / HWSP;
    int s = colg - n * HWSP;
    float* Yb = Y + (size_t)n * (CCH*(size_t)HWSP) + s;
    #pragma unroll
    for (int fm = 0; fm < 4; ++fm) {
      int mrow = m0 + wr*64 + fm*16 + ((lane >> 4) << 2);
      #pragma unroll
      for (int r = 0; r < 4; ++r)
        Yb[(size_t)(mrow + r) * HWSP] = acc[fm][fn][r];
    }
  }
}

extern "C" void kernel_launch(void* const* d_in, const int* in_sizes, int n_in,
                              void* d_out, int out_size, void* d_ws, size_t ws_size,
                              hipStream_t stream) {
  const float* X = (const float*)d_in[0];   // [16,512,56,56] f32
  const float* w = (const float*)d_in[1];   // [27] f32
  float* Y = (float*)d_out;

  float* h           = (float*)d_ws;                                // 2 KB
  unsigned short* Hm = (unsigned short*)((char*)d_ws + 4096);       // 512 KB

  k_h2    <<<CCH, 512, 0, stream>>>(w, h);
  k_buildH<<<CCH, 256, 0, stream>>>(h, Hm);

  const int nblk = (CCH/BM) * (NCOL/BN);    // 4 * 392 = 1568
  k_gemm  <<<nblk, 256, 0, stream>>>(X, Hm, Y);
}